// Round 1
// baseline (243.834 us; speedup 1.0000x reference)
//
#include <hip/hip_runtime.h>
#include <hip/hip_bf16.h>

#define NBANK 131072
#define DF 1024
#define NB 64

typedef float f32x4 __attribute__((ext_vector_type(4)));
typedef short bf16x8 __attribute__((ext_vector_type(8)));

__device__ __forceinline__ unsigned short f2bf(float f) {
    union { float f; unsigned u; } c; c.f = f;
    unsigned u = c.u;
    return (unsigned short)((u + 0x7FFFu + ((u >> 16) & 1u)) >> 16);
}

// Kernel A: L2-normalize the 64 input rows.
// Writes x_f32 (for the scatter update) and bf16 A-fragments pre-permuted
// into MFMA lane order: frag[(m>>4)*32 + ks][lane = (t&3)*16 + (m&15)],
// so kernel C's A-operand loads are fully coalesced (1KB/wave) and L2-hot.
__global__ __launch_bounds__(128) void knorm(const float* __restrict__ inputs,
                                             float* __restrict__ x_f32,
                                             bf16x8* __restrict__ xfrag) {
    int m = blockIdx.x;
    int t = threadIdx.x;          // handles k = t*8 .. t*8+7
    const f32x4* row = (const f32x4*)(inputs + (size_t)m * DF);
    f32x4 v0 = row[t * 2];
    f32x4 v1 = row[t * 2 + 1];
    float s = v0.x*v0.x + v0.y*v0.y + v0.z*v0.z + v0.w*v0.w
            + v1.x*v1.x + v1.y*v1.y + v1.z*v1.z + v1.w*v1.w;
    for (int o = 32; o > 0; o >>= 1) s += __shfl_xor(s, o);
    __shared__ float red[2];
    if ((t & 63) == 0) red[t >> 6] = s;
    __syncthreads();
    float tot = red[0] + red[1];
    float inv = 1.0f / fmaxf(sqrtf(tot), 1e-12f);
    v0 *= inv; v1 *= inv;
    f32x4* xr = (f32x4*)(x_f32 + (size_t)m * DF);
    xr[t * 2]     = v0;
    xr[t * 2 + 1] = v1;
    unsigned short h[8] = { f2bf(v0.x), f2bf(v0.y), f2bf(v0.z), f2bf(v0.w),
                            f2bf(v1.x), f2bf(v1.y), f2bf(v1.z), f2bf(v1.w) };
    int idx = ((m >> 4) * 32 + (t >> 2)) * 64 + (t & 3) * 16 + (m & 15);
    xfrag[idx] = *(bf16x8*)h;
}

// Kernel C: fused sim GEMM + bank copy.
// Per block: 16 bank rows. Stage f32 -> d_out copy (verbatim) and f32->bf16
// into LDS with XOR swizzle (kills the stride-2KB 16-way bank conflict).
// Then 4 waves (one 16-row M-tile each) x 32 K-steps of mfma 16x16x32 bf16.
__global__ __launch_bounds__(256) void kmain(const float* __restrict__ features,
                                             const bf16x8* __restrict__ xfrag,
                                             float* __restrict__ sim,
                                             float* __restrict__ outf) {
    __shared__ __align__(16) unsigned char tile[16 * 2048];
    int j0 = blockIdx.x * 16;
    int t = threadIdx.x;          // covers cols t*4 .. t*4+3 of each row
#pragma unroll 4
    for (int p = 0; p < 16; ++p) {
        const f32x4* src = (const f32x4*)(features + (size_t)(j0 + p) * DF) + t;
        f32x4 v = *src;
        *((f32x4*)(outf + (size_t)(j0 + p) * DF) + t) = v;   // bank copy
        unsigned lo = (unsigned)f2bf(v.x) | ((unsigned)f2bf(v.y) << 16);
        unsigned hi = (unsigned)f2bf(v.z) | ((unsigned)f2bf(v.w) << 16);
        uint2 pk; pk.x = lo; pk.y = hi;
        unsigned off = (unsigned)(p * 2048) + (((unsigned)(t * 8)) ^ ((unsigned)(p & 7) << 4));
        *(uint2*)(tile + off) = pk;
    }
    __syncthreads();

    int wave = t >> 6;
    int lane = t & 63;
    const bf16x8* af = xfrag + (size_t)(wave * 32) * 64 + lane;
    unsigned brow = lane & 15;
    unsigned bbase = brow * 2048;
    unsigned bswz = (brow & 7) << 4;
    unsigned bcol = (unsigned)(lane >> 4) * 16;
    f32x4 acc = {0.f, 0.f, 0.f, 0.f};
#pragma unroll 8
    for (int ks = 0; ks < 32; ++ks) {
        bf16x8 a = af[ks * 64];
        bf16x8 b = *(const bf16x8*)(tile + bbase + (((unsigned)(ks * 64) + bcol) ^ bswz));
        acc = __builtin_amdgcn_mfma_f32_16x16x32_bf16(a, b, acc, 0, 0, 0);
    }
    int m0 = wave * 16 + (lane >> 4) * 4;
    int n = j0 + (lane & 15);
#pragma unroll
    for (int r = 0; r < 4; ++r)
        sim[(size_t)(m0 + r) * NBANK + n] = acc[r] * 20.0f;   // 1/TEMP
}

// Kernel B: sequential momentum scatter-update, run AFTER kmain's copy.
// Block i acts only if step i is the LAST occurrence of its index; it replays
// the full chain of occurrences in order (exact lax.scan semantics for
// repeated indexes), renormalizing after each step with a block reduction.
__global__ __launch_bounds__(256) void kupdate(const float* __restrict__ features,
                                               const int* __restrict__ indexes,
                                               const float* __restrict__ x_f32,
                                               float* __restrict__ outf) {
    __shared__ int sidx[NB];
    __shared__ float red[4];
    int t = threadIdx.x;
    int bi = blockIdx.x;
    if (t < NB) sidx[t] = indexes[t];
    __syncthreads();
    int y = sidx[bi];
    for (int j = bi + 1; j < NB; ++j)
        if (sidx[j] == y) return;           // uniform across block: safe
    f32x4 cur = *((const f32x4*)(features + (size_t)y * DF) + t);
    for (int j = 0; j <= bi; ++j) {
        if (sidx[j] != y) continue;         // uniform across block
        f32x4 xv = *((const f32x4*)(x_f32 + (size_t)j * DF) + t);
        cur = cur * 0.2f + xv * 0.8f;
        float s = cur.x*cur.x + cur.y*cur.y + cur.z*cur.z + cur.w*cur.w;
        for (int o = 32; o > 0; o >>= 1) s += __shfl_xor(s, o);
        if ((t & 63) == 0) red[t >> 6] = s;
        __syncthreads();
        float tot = red[0] + red[1] + red[2] + red[3];
        __syncthreads();
        float inv = 1.0f / fmaxf(sqrtf(tot), 1e-12f);
        cur *= inv;
    }
    *((f32x4*)(outf + (size_t)y * DF) + t) = cur;
}

extern "C" void kernel_launch(void* const* d_in, const int* in_sizes, int n_in,
                              void* d_out, int out_size, void* d_ws, size_t ws_size,
                              hipStream_t stream) {
    const float* inputs   = (const float*)d_in[0];
    const int*   indexes  = (const int*)d_in[1];
    const float* features = (const float*)d_in[2];
    float* sim  = (float*)d_out;                       // [64 * 131072]
    float* outf = sim + (size_t)NB * NBANK;            // [131072 * 1024]
    float*  x_f32 = (float*)d_ws;                      // 256 KB
    bf16x8* xfrag = (bf16x8*)((char*)d_ws + (size_t)NB * DF * 4);  // 128 KB

    knorm<<<NB, 128, 0, stream>>>(inputs, x_f32, xfrag);
    kmain<<<NBANK / 16, 256, 0, stream>>>(features, xfrag, sim, outf);
    kupdate<<<NB, 256, 0, stream>>>(features, indexes, x_f32, outf);
}